// Round 1
// baseline (43.479 us; speedup 1.0000x reference)
//
#include <hip/hip_runtime.h>

// Problem constants
#define B_DIM 8
#define E_DIM 3
#define C_DIM 3
#define N_KNOTS 10
#define NSEG 9
#define NVALS 255
#define HW 589824            // 768*768
#define HW4 147456           // HW/4
#define OUT1_ELEMS 42467328  // 8*3*3*HW
constexpr float STEPF = 1.0f / 9.0f;

// ---------------------------------------------------------------------------
// Kernel A: per-spline coefficient computation (Thomas tridiag solve) + the
// 255-point "splines" output. 72 blocks (one per (b,e,c) spline), 256 threads.
// ---------------------------------------------------------------------------
__global__ __launch_bounds__(256) void spline_coeffs_kernel(
    const float* __restrict__ ys, float4* __restrict__ ws,
    float* __restrict__ splines_out)
{
    const int s = blockIdx.x;  // s = (b*3 + e)*3 + c, 0..71
    __shared__ float4 coef[NSEG];

    if (threadIdx.x == 0) {
        float y[N_KNOTS];
#pragma unroll
        for (int j = 0; j < N_KNOTS; ++j)
            y[j] = ys[s * N_KNOTS + j] + (float)j * STEPF;  // + identity

        // rhs = 6/h^2 * second differences = 486 * (y[i] - 2y[i+1] + y[i+2])
        float r[8];
#pragma unroll
        for (int i = 0; i < 8; ++i)
            r[i] = 486.0f * (y[i] - 2.0f * y[i + 1] + y[i + 2]);

        // Thomas solve of tridiag(1,4,1) x = r  (n=8)
        float cp[8], dp[8];
        cp[0] = 0.25f;
        dp[0] = r[0] * 0.25f;
#pragma unroll
        for (int i = 1; i < 8; ++i) {
            float m = 1.0f / (4.0f - cp[i - 1]);
            cp[i] = m;
            dp[i] = (r[i] - dp[i - 1]) * m;
        }
        float M[N_KNOTS];
        M[0] = 0.0f;
        M[9] = 0.0f;
        M[8] = dp[7];
#pragma unroll
        for (int i = 6; i >= 0; --i)
            M[i + 1] = dp[i] - cp[i] * M[i + 2];

#pragma unroll
        for (int k = 0; k < NSEG; ++k) {
            float4 cf;
            cf.x = (M[k + 1] - M[k]) * 1.5f;                       // a = dM/(6h)
            cf.y = M[k] * 0.5f;                                    // b = M/2
            cf.z = (y[k + 1] - y[k]) * 9.0f
                   - (M[k + 1] + 2.0f * M[k]) * (1.0f / 54.0f);    // c
            cf.w = y[k];                                           // d
            coef[k] = cf;
            ws[s * NSEG + k] = cf;
        }
    }
    __syncthreads();

    const int t = threadIdx.x;
    if (t < NVALS) {
        float v = (float)t * (1.0f / 255.0f);
        float tx = fminf(fmaxf(v * 9.0f, 0.0f), 8.0f);
        float xif = floorf(tx);
        int xi = (int)xif;
        float xf = v - xif * STEPF;
        float4 cf = coef[xi];
        splines_out[s * NVALS + t] =
            ((cf.x * xf + cf.y) * xf + cf.z) * xf + cf.w;
    }
}

// ---------------------------------------------------------------------------
// Kernel B: main evaluation. grid = (144, 24): y = plane (b*3+c), x = chunk.
// Each thread processes 4 float4s; per element evaluates e=0,1,2 splines.
// ---------------------------------------------------------------------------
__device__ __forceinline__ void eval3(float x, const float4 (&coef)[3][NSEG],
                                      float& o0, float& o1, float& o2)
{
    float tx = fminf(fmaxf(x * 9.0f, 0.0f), 8.0f);
    float xif = floorf(tx);
    int xi = (int)xif;
    float xf = x - xif * STEPF;
    float4 c0 = coef[0][xi];
    float4 c1 = coef[1][xi];
    float4 c2 = coef[2][xi];
    o0 = ((c0.x * xf + c0.y) * xf + c0.z) * xf + c0.w;
    o1 = ((c1.x * xf + c1.y) * xf + c1.z) * xf + c1.w;
    o2 = ((c2.x * xf + c2.y) * xf + c2.z) * xf + c2.w;
}

__global__ __launch_bounds__(256) void spline_eval_kernel(
    const float4* __restrict__ batch, const float4* __restrict__ ws,
    float4* __restrict__ out)
{
    const int plane = blockIdx.y;        // b*3 + c
    const int b = plane / 3;
    const int c = plane % 3;

    __shared__ float4 coef[E_DIM][NSEG];
    const int t = threadIdx.x;
    if (t < E_DIM * NSEG) {
        int e = t / NSEG, k = t % NSEG;
        coef[e][k] = ws[(b * 9 + e * 3 + c) * NSEG + k];
    }
    __syncthreads();

    const float4* src = batch + (size_t)plane * HW4;
    float4* dst0 = out + (size_t)(b * 9 + 0 * 3 + c) * HW4;
    float4* dst1 = out + (size_t)(b * 9 + 1 * 3 + c) * HW4;
    float4* dst2 = out + (size_t)(b * 9 + 2 * 3 + c) * HW4;

    const int idx0 = blockIdx.x * 1024 + t;
#pragma unroll
    for (int kk = 0; kk < 4; ++kk) {
        int idx = idx0 + kk * 256;
        float4 x = src[idx];
        float4 r0, r1, r2;
        eval3(x.x, coef, r0.x, r1.x, r2.x);
        eval3(x.y, coef, r0.y, r1.y, r2.y);
        eval3(x.z, coef, r0.z, r1.z, r2.z);
        eval3(x.w, coef, r0.w, r1.w, r2.w);
        dst0[idx] = r0;
        dst1[idx] = r1;
        dst2[idx] = r2;
    }
}

// ---------------------------------------------------------------------------
extern "C" void kernel_launch(void* const* d_in, const int* in_sizes, int n_in,
                              void* d_out, int out_size, void* d_ws, size_t ws_size,
                              hipStream_t stream)
{
    const float* batch = (const float*)d_in[0];
    const float* ys = (const float*)d_in[1];
    float* out = (float*)d_out;
    float4* ws = (float4*)d_ws;

    // Kernel A: coefficients into ws + splines tail output
    spline_coeffs_kernel<<<dim3(B_DIM * E_DIM * C_DIM), dim3(256), 0, stream>>>(
        ys, ws, out + OUT1_ELEMS);

    // Kernel B: main per-pixel evaluation
    spline_eval_kernel<<<dim3(144, 24), dim3(256), 0, stream>>>(
        (const float4*)batch, (const float4*)ws, (float4*)out);
}

// Round 2
// 39.504 us; speedup vs baseline: 1.1006x; 1.1006x over previous
//
#include <hip/hip_runtime.h>

#define NSEG 9
#define NVALS 255
#define HW4 147456           // 768*768/4 float4 per plane
#define OUT1_ELEMS 42467328  // 8*3*3*768*768
constexpr float STEPF = 1.0f / 9.0f;

typedef float f32x4 __attribute__((ext_vector_type(4)));

// ---------------------------------------------------------------------------
// Fully fused kernel. grid = (144, 24): y = plane (b*3+c), x = chunk of plane.
//  - threads 0..2 compute the 3 e-spline coefficient sets via Thomas solve
//  - all threads evaluate 4 float4s of the input plane for e=0,1,2
//  - blockIdx.x==0 blocks additionally emit the 255-entry `splines` output
// ---------------------------------------------------------------------------
__global__ __launch_bounds__(256) void spline_fused_kernel(
    const float4* __restrict__ batch, const float* __restrict__ ys,
    float* __restrict__ out)
{
    const int plane = blockIdx.y;  // b*3 + c
    const int b = plane / 3;
    const int c = plane - b * 3;

    __shared__ float4 coef[3][NSEG];
    const int t = threadIdx.x;

    if (t < 3) {
        const int e = t;
        const float* yp = ys + ((size_t)(b * 3 + e) * 3 + c) * 10;
        float y[10];
#pragma unroll
        for (int j = 0; j < 10; ++j)
            y[j] = yp[j] + (float)j * STEPF;  // + identity ramp

        // rhs = 6/h^2 * second differences = 486 * (y[i] - 2y[i+1] + y[i+2])
        float r[8];
#pragma unroll
        for (int i = 0; i < 8; ++i)
            r[i] = 486.0f * (y[i] - 2.0f * y[i + 1] + y[i + 2]);

        // Thomas solve of tridiag(1,4,1) M = r  (n=8), M[0]=M[9]=0
        float cp[8], dp[8];
        cp[0] = 0.25f;
        dp[0] = r[0] * 0.25f;
#pragma unroll
        for (int i = 1; i < 8; ++i) {
            float m = 1.0f / (4.0f - cp[i - 1]);
            cp[i] = m;
            dp[i] = (r[i] - dp[i - 1]) * m;
        }
        float M[10];
        M[0] = 0.0f; M[9] = 0.0f; M[8] = dp[7];
#pragma unroll
        for (int i = 6; i >= 0; --i)
            M[i + 1] = dp[i] - cp[i] * M[i + 2];

#pragma unroll
        for (int k = 0; k < NSEG; ++k) {
            float4 cf;
            cf.x = (M[k + 1] - M[k]) * 1.5f;                     // a = dM/(6h)
            cf.y = M[k] * 0.5f;                                  // b = M/2
            cf.z = (y[k + 1] - y[k]) * 9.0f
                   - (M[k + 1] + 2.0f * M[k]) * (1.0f / 54.0f);  // c
            cf.w = y[k];                                         // d
            coef[e][k] = cf;
        }
    }
    __syncthreads();

    // ---- splines tail (24 blocks only, 765 evals total) ----
    if (blockIdx.x == 0 && t < NVALS) {
        float v = (float)t * (1.0f / 255.0f);
        float xif = floorf(fminf(v * 9.0f, 8.0f));
        int xi = (int)xif;
        float xf = v - xif * STEPF;
        float* sp = out + OUT1_ELEMS;
#pragma unroll
        for (int e = 0; e < 3; ++e) {
            float4 cf = coef[e][xi];
            sp[((size_t)(b * 3 + e) * 3 + c) * NVALS + t] =
                ((cf.x * xf + cf.y) * xf + cf.z) * xf + cf.w;
        }
    }

    // ---- main evaluation ----
    const float4* src = batch + (size_t)plane * HW4;
    f32x4* dst0 = (f32x4*)out + (size_t)(b * 9 + 0 + c) * HW4;
    f32x4* dst1 = (f32x4*)out + (size_t)(b * 9 + 3 + c) * HW4;
    f32x4* dst2 = (f32x4*)out + (size_t)(b * 9 + 6 + c) * HW4;

    const int idx0 = blockIdx.x * 1024 + t;
#pragma unroll
    for (int kk = 0; kk < 4; ++kk) {
        int idx = idx0 + kk * 256;
        float4 x = src[idx];
        f32x4 r0, r1, r2;
#pragma unroll
        for (int l = 0; l < 4; ++l) {
            float xv = (&x.x)[l];
            float xif = floorf(fminf(fmaxf(xv * 9.0f, 0.0f), 8.0f));
            int xi = (int)xif;
            float xf = xv - xif * STEPF;
            float4 c0 = coef[0][xi];
            float4 c1 = coef[1][xi];
            float4 c2 = coef[2][xi];
            r0[l] = ((c0.x * xf + c0.y) * xf + c0.z) * xf + c0.w;
            r1[l] = ((c1.x * xf + c1.y) * xf + c1.z) * xf + c1.w;
            r2[l] = ((c2.x * xf + c2.y) * xf + c2.z) * xf + c2.w;
        }
        __builtin_nontemporal_store(r0, dst0 + idx);
        __builtin_nontemporal_store(r1, dst1 + idx);
        __builtin_nontemporal_store(r2, dst2 + idx);
    }
}

// ---------------------------------------------------------------------------
extern "C" void kernel_launch(void* const* d_in, const int* in_sizes, int n_in,
                              void* d_out, int out_size, void* d_ws, size_t ws_size,
                              hipStream_t stream)
{
    const float* batch = (const float*)d_in[0];
    const float* ys = (const float*)d_in[1];
    float* out = (float*)d_out;

    spline_fused_kernel<<<dim3(144, 24), dim3(256), 0, stream>>>(
        (const float4*)batch, ys, out);
}